// Round 3
// baseline (14275.233 us; speedup 1.0000x reference)
//
#include <hip/hip_runtime.h>
#include <cstdint>
#include <cstddef>

#define NV 50000
#define NE 300
#define NH 256
#define NR 2048
#define NL0 128
#define NLR 64
#define NS 2049      // R + 1
#define G3 768       // 3*H

typedef unsigned long long ull;

// ---------------- workspace layout ----------------
static constexpr size_t alignUp(size_t x, size_t a) { return (x + a - 1) / a * a; }
static constexpr size_t OFF_HCOM_F = 0;                         // 2*256 u64 (double-buffered)
static constexpr size_t OFF_HCOM_B = 4096;                      // 2*256 u64
static constexpr size_t OFF_CTX    = 8192;                      // 256 f32
static constexpr size_t OFF_CLAIM  = 9216;                      // 2 u32 role counters
static constexpr size_t ZERO_BYTES = 9232;
static constexpr size_t OFF_SCORES = 9472;                      // 2049 f32
static constexpr size_t OFF_X      = alignUp(OFF_SCORES + (size_t)NS*4, 256);   // 2049*300 f32
static constexpr size_t OFF_GI_F   = alignUp(OFF_X + (size_t)NS*NE*4, 256);     // 2049*768 f32
static constexpr size_t OFF_GI_B   = alignUp(OFF_GI_F + (size_t)NS*G3*4, 256);  // 2049*768 f32
static constexpr size_t OFF_OUT2   = alignUp(OFF_GI_B + (size_t)NS*G3*4, 256);  // 2049*512 f32

// ---------------- 1) X = [orig_sum ; reply_sums] ----------------
__global__ __launch_bounds__(320) void embed_sum_kernel(
    const int* __restrict__ otok, const int* __restrict__ rtok,
    const int* __restrict__ rlen, const float* __restrict__ embed,
    float* __restrict__ X)
{
    const int b = blockIdx.x;      // 0..2048
    const int e = threadIdx.x;     // < 300 active
    if (e >= NE) return;
    float acc = 0.f;
    if (b == 0) {
        for (int t = 0; t < NL0; ++t) {
            int tok = otok[t];
            acc += embed[(size_t)tok * NE + e];
        }
    } else {
        const int r = b - 1;
        const int L = rlen[r];
        const int* tr = rtok + (size_t)r * NLR;
        for (int t = 0; t < L; ++t) {
            int tok = tr[t];
            acc += embed[(size_t)tok * NE + e];
        }
    }
    X[(size_t)b * NE + e] = acc;
}

// ---------------- 2) C[M,N] = A[M,K] @ B[N,K]^T + bias[N] ----------------
__global__ __launch_bounds__(256) void gemm_abt(
    const float* __restrict__ A, const float* __restrict__ B,
    const float* __restrict__ bias, float* __restrict__ C,
    int M, int N, int K, int ldc)
{
    __shared__ float As[16][65];
    __shared__ float Bs[16][65];
    const int bm = blockIdx.x * 64, bn = blockIdx.y * 64;
    const int tid = threadIdx.x;
    const int tx = tid & 15, ty = tid >> 4;
    float acc[4][4] = {};
    for (int k0 = 0; k0 < K; k0 += 16) {
        #pragma unroll
        for (int i = 0; i < 4; ++i) {
            int l = tid + 256 * i;
            int mm = l >> 4, kk = l & 15;
            int gm = bm + mm, gk = k0 + kk;
            As[kk][mm] = (gm < M && gk < K) ? A[(size_t)gm * K + gk] : 0.f;
            int gn = bn + mm;
            Bs[kk][mm] = (gk < K) ? B[(size_t)gn * K + gk] : 0.f;
        }
        __syncthreads();
        #pragma unroll
        for (int kk = 0; kk < 16; ++kk) {
            float a0 = As[kk][ty], a1 = As[kk][ty+16], a2 = As[kk][ty+32], a3 = As[kk][ty+48];
            float b0 = Bs[kk][tx], b1 = Bs[kk][tx+16], b2 = Bs[kk][tx+32], b3 = Bs[kk][tx+48];
            acc[0][0] += a0*b0; acc[0][1] += a0*b1; acc[0][2] += a0*b2; acc[0][3] += a0*b3;
            acc[1][0] += a1*b0; acc[1][1] += a1*b1; acc[1][2] += a1*b2; acc[1][3] += a1*b3;
            acc[2][0] += a2*b0; acc[2][1] += a2*b1; acc[2][2] += a2*b2; acc[2][3] += a2*b3;
            acc[3][0] += a3*b0; acc[3][1] += a3*b1; acc[3][2] += a3*b2; acc[3][3] += a3*b3;
        }
        __syncthreads();
    }
    #pragma unroll
    for (int i = 0; i < 4; ++i) {
        int gm = bm + ty + 16 * i;
        if (gm >= M) continue;
        #pragma unroll
        for (int j = 0; j < 4; ++j) {
            int gn = bn + tx + 16 * j;
            C[(size_t)gm * ldc + gn] = acc[i][j] + bias[gn];
        }
    }
}

// ---------------- DPP helper (ctrl must be compile-time constant) ----------------
template <int CTRL>
__device__ __forceinline__ float dpp_add(float x) {
    int y = __builtin_amdgcn_update_dpp(0, __float_as_int(x), CTRL, 0xF, 0xF, false);
    return x + __int_as_float(y);
}

// ---------------- 3) bidirectional GRU recurrence (XCD-local, register-resident) ----------
// Launch 512 blocks x 256 threads. Blocks read HW_REG_XCC_ID:
//   XCD 0 -> first 4 claimers = forward WGs (w=0..3), XCD 1 -> backward. Others exit.
// Each WG: 64 outputs, 192 Whh rows x 256 cols held ENTIRELY in VGPRs (192 f32/lane).
// Lane (g=tid>>3, q=tid&7): rows wgrow = g+32j (j=0..5), cols [32q,32q+32).
// q-reduction via DPP (quad_perm x2 + row_half_mirror) — no DS pipe.
// Cross-WG h exchange: tagged u64, parity double-buffered, via NON-sc1 global atomics
// (execute in the shared per-XCD L2 — all 4 WGs of a direction are on the same XCD).
__global__ __launch_bounds__(256, 1) void gru_kernel(
    const float* __restrict__ Whh_f, const float* __restrict__ bhh_f,
    const float* __restrict__ Whh_b, const float* __restrict__ bhh_b,
    const float* __restrict__ gi_f, const float* __restrict__ gi_b,
    float* __restrict__ out2,
    ull* __restrict__ hcom_f, ull* __restrict__ hcom_b,
    unsigned int* __restrict__ claim)
{
    unsigned int xcc;
    asm volatile("s_getreg_b32 %0, hwreg(HW_REG_XCC_ID)" : "=s"(xcc));
    xcc &= 0xfu;

    __shared__ int role_s;
    if (threadIdx.x == 0) {
        int r = 99;
        if (xcc < 2u) r = (int)atomicAdd(&claim[xcc], 1u);
        role_s = r;
    }
    __syncthreads();
    const int role = role_s;
    if (xcc >= 2u || role >= 4) return;

    const int dir = (int)xcc;          // 0 = fwd (XCD0), 1 = bwd (XCD1)
    const int w   = role;              // owns outputs [64w, 64w+64)
    const int tid = threadIdx.x;
    const int g   = tid >> 3;          // row group 0..31
    const int q   = tid & 7;           // col slice: cols [32q, 32q+32)

    const float* Whh = dir ? Whh_b : Whh_f;
    const float* bhh = dir ? bhh_b : bhh_f;
    const float* gi  = dir ? gi_b  : gi_f;
    ull* hcom = dir ? hcom_b : hcom_f;

    // ---- stage weights into registers: 6 rows x 8 float4 = 192 floats/lane ----
    float4 wreg[6][8];
    #pragma unroll
    for (int j = 0; j < 6; ++j) {
        const int wgrow = g + 32 * j;
        const int grow  = ((wgrow >> 6) << 8) + (w << 6) + (wgrow & 63);
        const float4* src = (const float4*)(Whh + (size_t)grow * NH + (q << 5));
        #pragma unroll
        for (int c = 0; c < 8; ++c) wreg[j][c] = src[c];
    }

    __shared__ float4 h4[64];          // h state (256 f32)
    __shared__ float  ghs[192];
    __shared__ float  bh_s[192];
    float* h_s = (float*)h4;

    if (tid < 192) {
        const int grow = ((tid >> 6) << 8) + (w << 6) + (tid & 63);
        bh_s[tid] = bhh[grow];
    }
    h_s[tid] = 0.f;
    __syncthreads();

    for (int t = 0; t < NS; ++t) {
        const int s = dir ? (NS - 1 - t) : t;

        // input-gate prefetch (independent of h) by the gate wave
        float gir = 0.f, giz = 0.f, gin = 0.f;
        if (tid < 64) {
            const float* gp = gi + (size_t)s * G3 + (w << 6) + tid;
            gir = gp[0]; giz = gp[NH]; gin = gp[2 * NH];
        }

        // ---- matvec: read h cols [32q,32q+32) (q-rotated -> conflict-free) ----
        float4 hv[8];
        #pragma unroll
        for (int c = 0; c < 8; ++c) {
            const int kk = (c + q) & 7;
            hv[kk] = h4[(q << 3) + kk];
        }
        #pragma unroll
        for (int j = 0; j < 6; ++j) {
            float4 a = make_float4(0.f, 0.f, 0.f, 0.f);
            #pragma unroll
            for (int c = 0; c < 8; ++c) {
                a.x += wreg[j][c].x * hv[c].x;
                a.y += wreg[j][c].y * hv[c].y;
                a.z += wreg[j][c].z * hv[c].z;
                a.w += wreg[j][c].w * hv[c].w;
            }
            float r = (a.x + a.y) + (a.z + a.w);
            r = dpp_add<0x0B1>(r);   // quad_perm [1,0,3,2]  (sum lane^1)
            r = dpp_add<0x04E>(r);   // quad_perm [2,3,0,1]  (sum lane^2)
            r = dpp_add<0x141>(r);   // row_half_mirror      (sum other quad)
            if (q == 0) {
                const int wgrow = g + 32 * j;
                ghs[wgrow] = r + bh_s[wgrow];
            }
        }
        __syncthreads();   // S1: ghs ready; all matvec reads of h done

        if (tid < 64) {
            const int i = tid;
            const float r  = 1.f / (1.f + __expf(-(gir + ghs[i])));
            const float z  = 1.f / (1.f + __expf(-(giz + ghs[64 + i])));
            const float n  = tanhf(gin + r * ghs[128 + i]);
            const float hn = (1.f - z) * n + z * h_s[(w << 6) + i];
            out2[(size_t)s * (2 * NH) + dir * NH + (w << 6) + i] = hn;
            const ull pv = ((ull)(unsigned)(t + 1) << 32) | (ull)__float_as_uint(hn);
            const ull addr = (ull)(uintptr_t)(hcom + ((t & 1) << 8) + (w << 6) + i);
            // XCD-local L2 atomic store (no sc1 -> stays in this XCD's L2)
            asm volatile("global_atomic_swap_x2 %0, %1, off" :: "v"(addr), "v"(pv) : "memory");
            h_s[(w << 6) + i] = hn;
        } else if (t < NS - 1) {
            const int k   = tid - 64;                       // 0..191
            const int idx = (k < (w << 6)) ? k : k + 64;    // skip own 64
            const ull addr = (ull)(uintptr_t)(hcom + ((t & 1) << 8) + idx);
            const unsigned want = (unsigned)(t + 1);
            const ull zero = 0ull;
            ull v;
            do {
                // L2-local atomic read (add 0, sc0 = return old); never leaves the XCD
                asm volatile("global_atomic_add_x2 %0, %1, %2, off sc0\n\ts_waitcnt vmcnt(0)"
                             : "=v"(v) : "v"(addr), "v"(zero) : "memory");
            } while ((unsigned)(v >> 32) != want);
            h_s[idx] = __uint_as_float((unsigned)v);
        }
        __syncthreads();   // S2: h fully updated
    }
}

// ---------------- 4) scores[s] = dot(output[s], h_f + h_b) ----------------
__global__ __launch_bounds__(256) void scores_kernel(
    const float* __restrict__ outp, const float* __restrict__ out2,
    float* __restrict__ scores)
{
    const int s = blockIdx.x, m = threadIdx.x;
    float hs = out2[(size_t)(NS - 1) * (2 * NH) + m] + out2[NH + m];
    float v = outp[(size_t)s * NH + m] * hs;
    #pragma unroll
    for (int o = 32; o > 0; o >>= 1) v += __shfl_down(v, o);
    __shared__ float p[4];
    if ((m & 63) == 0) p[m >> 6] = v;
    __syncthreads();
    if (m == 0) scores[s] = p[0] + p[1] + p[2] + p[3];
}

// ---------------- 5) softmax over 2049 scores (in place) ----------------
__global__ __launch_bounds__(1024) void softmax_kernel(float* __restrict__ sc)
{
    const int tid = threadIdx.x;
    __shared__ float red[16];
    float x0 = (tid < NS) ? sc[tid] : -3.0e38f;
    float x1 = (tid + 1024 < NS) ? sc[tid + 1024] : -3.0e38f;
    float mx = fmaxf(x0, x1);
    #pragma unroll
    for (int o = 32; o > 0; o >>= 1) mx = fmaxf(mx, __shfl_xor(mx, o));
    if ((tid & 63) == 0) red[tid >> 6] = mx;
    __syncthreads();
    if (tid == 0) {
        float m = red[0];
        for (int i = 1; i < 16; ++i) m = fmaxf(m, red[i]);
        red[0] = m;
    }
    __syncthreads();
    const float gmax = red[0];
    float e0 = (tid < NS) ? __expf(x0 - gmax) : 0.f;
    float e1 = (tid + 1024 < NS) ? __expf(x1 - gmax) : 0.f;
    float sm = e0 + e1;
    #pragma unroll
    for (int o = 32; o > 0; o >>= 1) sm += __shfl_xor(sm, o);
    __syncthreads();
    if ((tid & 63) == 0) red[tid >> 6] = sm;
    __syncthreads();
    if (tid == 0) {
        float su = 0.f;
        for (int i = 0; i < 16; ++i) su += red[i];
        red[1] = 1.f / su;
    }
    __syncthreads();
    const float inv = red[1];
    if (tid < NS) sc[tid] = e0 * inv;
    if (tid + 1024 < NS) sc[tid + 1024] = e1 * inv;
}

// ---------------- 6) ctx[m] += sum_s w[s]*output[s][m] ----------------
__global__ __launch_bounds__(256) void ctx_kernel(
    const float* __restrict__ outp, const float* __restrict__ w,
    float* __restrict__ ctx)
{
    const int m = threadIdx.x;
    const int s0 = blockIdx.x * 128;
    const int s1 = min(s0 + 128, NS);
    float acc = 0.f;
    for (int s = s0; s < s1; ++s) acc += w[s] * outp[(size_t)s * NH + m];
    atomicAdd(&ctx[m], acc);
}

// ---------------- 7) result + loss ----------------
__global__ __launch_bounds__(256) void final_kernel(
    const float* __restrict__ ctx, const float* __restrict__ Wo,
    const float* __restrict__ bo, const float* __restrict__ label,
    float* __restrict__ dout)
{
    const int m = threadIdx.x;
    float v = ctx[m] * Wo[m];
    #pragma unroll
    for (int o = 32; o > 0; o >>= 1) v += __shfl_down(v, o);
    __shared__ float p[4];
    if ((m & 63) == 0) p[m >> 6] = v;
    __syncthreads();
    if (m == 0) {
        float x = p[0] + p[1] + p[2] + p[3] + bo[0];
        float result = 1.f / (1.f + __expf(-x));
        float d = label[0] - result;
        dout[(size_t)NS * NH]     = d * d;
        dout[(size_t)NS * NH + 1] = result;
    }
}

extern "C" void kernel_launch(void* const* d_in, const int* in_sizes, int n_in,
                              void* d_out, int out_size, void* d_ws, size_t ws_size,
                              hipStream_t stream)
{
    const int*   otok  = (const int*)d_in[0];
    const int*   rtok  = (const int*)d_in[1];
    const int*   rlen  = (const int*)d_in[2];
    const float* label = (const float*)d_in[3];
    const float* embed = (const float*)d_in[4];
    const float* Wih_f = (const float*)d_in[5];
    const float* Whh_f = (const float*)d_in[6];
    const float* bih_f = (const float*)d_in[7];
    const float* bhh_f = (const float*)d_in[8];
    const float* Wih_b = (const float*)d_in[9];
    const float* Whh_b = (const float*)d_in[10];
    const float* bih_b = (const float*)d_in[11];
    const float* bhh_b = (const float*)d_in[12];
    const float* Wl    = (const float*)d_in[13];
    const float* bl    = (const float*)d_in[14];
    const float* Wo    = (const float*)d_in[15];
    const float* bo    = (const float*)d_in[16];

    char* ws = (char*)d_ws;
    ull* hcom_f = (ull*)(ws + OFF_HCOM_F);
    ull* hcom_b = (ull*)(ws + OFF_HCOM_B);
    float* ctx    = (float*)(ws + OFF_CTX);
    unsigned int* claim = (unsigned int*)(ws + OFF_CLAIM);
    float* scores = (float*)(ws + OFF_SCORES);
    float* X      = (float*)(ws + OFF_X);
    float* gi_f   = (float*)(ws + OFF_GI_F);
    float* gi_b   = (float*)(ws + OFF_GI_B);
    float* out2   = (float*)(ws + OFF_OUT2);
    float* outp   = (float*)d_out;

    // zero comm tags + ctx + claim counters (graph-capture-safe)
    (void)hipMemsetAsync(d_ws, 0, ZERO_BYTES, stream);

    embed_sum_kernel<<<NS, 320, 0, stream>>>(otok, rtok, rlen, embed, X);

    gemm_abt<<<dim3(33, 12), 256, 0, stream>>>(X, Wih_f, bih_f, gi_f, NS, G3, NE, G3);
    gemm_abt<<<dim3(33, 12), 256, 0, stream>>>(X, Wih_b, bih_b, gi_b, NS, G3, NE, G3);

    gru_kernel<<<512, 256, 0, stream>>>(Whh_f, bhh_f, Whh_b, bhh_b,
                                        gi_f, gi_b, out2, hcom_f, hcom_b, claim);

    gemm_abt<<<dim3(33, 4), 256, 0, stream>>>(out2, Wl, bl, outp, NS, NH, 2 * NH, NH);

    scores_kernel<<<NS, 256, 0, stream>>>(outp, out2, scores);
    softmax_kernel<<<1, 1024, 0, stream>>>(scores);
    ctx_kernel<<<(NS + 127) / 128, 256, 0, stream>>>(outp, scores, ctx);
    final_kernel<<<1, 256, 0, stream>>>(ctx, Wo, bo, label, (float*)d_out);
}

// Round 5
// 14148.923 us; speedup vs baseline: 1.0089x; 1.0089x over previous
//
#include <hip/hip_runtime.h>
#include <cstdint>
#include <cstddef>

#define NV 50000
#define NE 300
#define NH 256
#define NR 2048
#define NL0 128
#define NLR 64
#define NS 2049      // R + 1
#define G3 768       // 3*H

typedef unsigned long long ull;

// ---------------- workspace layout ----------------
static constexpr size_t alignUp(size_t x, size_t a) { return (x + a - 1) / a * a; }
static constexpr size_t OFF_HCOM_F = 0;                         // 2*256 u64 (double-buffered)
static constexpr size_t OFF_HCOM_B = 4096;                      // 2*256 u64
static constexpr size_t OFF_CTX    = 8192;                      // 256 f32
static constexpr size_t OFF_CLAIM  = 9216;                      // 2 u32 role counters
static constexpr size_t ZERO_BYTES = 9232;
static constexpr size_t OFF_SCORES = 9472;                      // 2049 f32
static constexpr size_t OFF_X      = alignUp(OFF_SCORES + (size_t)NS*4, 256);   // 2049*300 f32
static constexpr size_t OFF_GI_F   = alignUp(OFF_X + (size_t)NS*NE*4, 256);     // 2049*768 f32
static constexpr size_t OFF_GI_B   = alignUp(OFF_GI_F + (size_t)NS*G3*4, 256);  // 2049*768 f32
static constexpr size_t OFF_OUT2   = alignUp(OFF_GI_B + (size_t)NS*G3*4, 256);  // 2049*512 f32

// ---------------- 1) X = [orig_sum ; reply_sums] ----------------
__global__ __launch_bounds__(320) void embed_sum_kernel(
    const int* __restrict__ otok, const int* __restrict__ rtok,
    const int* __restrict__ rlen, const float* __restrict__ embed,
    float* __restrict__ X)
{
    const int b = blockIdx.x;      // 0..2048
    const int e = threadIdx.x;     // < 300 active
    if (e >= NE) return;
    float acc = 0.f;
    if (b == 0) {
        for (int t = 0; t < NL0; ++t) {
            int tok = otok[t];
            acc += embed[(size_t)tok * NE + e];
        }
    } else {
        const int r = b - 1;
        const int L = rlen[r];
        const int* tr = rtok + (size_t)r * NLR;
        for (int t = 0; t < L; ++t) {
            int tok = tr[t];
            acc += embed[(size_t)tok * NE + e];
        }
    }
    X[(size_t)b * NE + e] = acc;
}

// ---------------- 2) C[M,N] = A[M,K] @ B[N,K]^T + bias[N] ----------------
__global__ __launch_bounds__(256) void gemm_abt(
    const float* __restrict__ A, const float* __restrict__ B,
    const float* __restrict__ bias, float* __restrict__ C,
    int M, int N, int K, int ldc)
{
    __shared__ float As[16][65];
    __shared__ float Bs[16][65];
    const int bm = blockIdx.x * 64, bn = blockIdx.y * 64;
    const int tid = threadIdx.x;
    const int tx = tid & 15, ty = tid >> 4;
    float acc[4][4] = {};
    for (int k0 = 0; k0 < K; k0 += 16) {
        #pragma unroll
        for (int i = 0; i < 4; ++i) {
            int l = tid + 256 * i;
            int mm = l >> 4, kk = l & 15;
            int gm = bm + mm, gk = k0 + kk;
            As[kk][mm] = (gm < M && gk < K) ? A[(size_t)gm * K + gk] : 0.f;
            int gn = bn + mm;
            Bs[kk][mm] = (gk < K) ? B[(size_t)gn * K + gk] : 0.f;
        }
        __syncthreads();
        #pragma unroll
        for (int kk = 0; kk < 16; ++kk) {
            float a0 = As[kk][ty], a1 = As[kk][ty+16], a2 = As[kk][ty+32], a3 = As[kk][ty+48];
            float b0 = Bs[kk][tx], b1 = Bs[kk][tx+16], b2 = Bs[kk][tx+32], b3 = Bs[kk][tx+48];
            acc[0][0] += a0*b0; acc[0][1] += a0*b1; acc[0][2] += a0*b2; acc[0][3] += a0*b3;
            acc[1][0] += a1*b0; acc[1][1] += a1*b1; acc[1][2] += a1*b2; acc[1][3] += a1*b3;
            acc[2][0] += a2*b0; acc[2][1] += a2*b1; acc[2][2] += a2*b2; acc[2][3] += a2*b3;
            acc[3][0] += a3*b0; acc[3][1] += a3*b1; acc[3][2] += a3*b2; acc[3][3] += a3*b3;
        }
        __syncthreads();
    }
    #pragma unroll
    for (int i = 0; i < 4; ++i) {
        int gm = bm + ty + 16 * i;
        if (gm >= M) continue;
        #pragma unroll
        for (int j = 0; j < 4; ++j) {
            int gn = bn + tx + 16 * j;
            C[(size_t)gm * ldc + gn] = acc[i][j] + bias[gn];
        }
    }
}

// ---------------- DPP helper (ctrl must be compile-time constant) ----------------
template <int CTRL>
__device__ __forceinline__ float dpp_add(float x) {
    int y = __builtin_amdgcn_update_dpp(0, __float_as_int(x), CTRL, 0xF, 0xF, false);
    return x + __int_as_float(y);
}

// ---------------- 3) bidirectional GRU recurrence (XCD-local, register-resident) ----------
// Launch 512 blocks x 256 threads. Blocks read HW_REG_XCC_ID:
//   XCD 0 -> first 4 claimers = forward WGs (w=0..3), XCD 1 -> backward. Others exit.
// Each WG: 64 outputs, 192 Whh rows x 256 cols staged into the register file (192 f32/lane).
// q-reduction via DPP (quad_perm x2 + row_half_mirror) — no DS pipe.
// Cross-WG h exchange: tagged u64 (tag<<32|bits), parity double-buffered, via
// __hip_atomic_store / __hip_atomic_load RELAXED+AGENT — compiler emits the correct
// gfx950 coherence bits (R1-proven live & correct; non-RMW so no write storm like R3).
__global__ __launch_bounds__(256, 1) void gru_kernel(
    const float* __restrict__ Whh_f, const float* __restrict__ bhh_f,
    const float* __restrict__ Whh_b, const float* __restrict__ bhh_b,
    const float* __restrict__ gi_f, const float* __restrict__ gi_b,
    float* __restrict__ out2,
    ull* __restrict__ hcom_f, ull* __restrict__ hcom_b,
    unsigned int* __restrict__ claim)
{
    unsigned int xcc;
    asm volatile("s_getreg_b32 %0, hwreg(HW_REG_XCC_ID)" : "=s"(xcc));
    xcc &= 0xfu;

    __shared__ int role_s;
    if (threadIdx.x == 0) {
        int r = 99;
        if (xcc < 2u) r = (int)atomicAdd(&claim[xcc], 1u);
        role_s = r;
    }
    __syncthreads();
    const int role = role_s;
    if (xcc >= 2u || role >= 4) return;

    const int dir = (int)xcc;          // 0 = fwd (XCD0), 1 = bwd (XCD1)
    const int w   = role;              // owns outputs [64w, 64w+64)
    const int tid = threadIdx.x;
    const int g   = tid >> 3;          // row group 0..31
    const int q   = tid & 7;           // col slice: cols [32q, 32q+32)

    const float* Whh = dir ? Whh_b : Whh_f;
    const float* bhh = dir ? bhh_b : bhh_f;
    const float* gi  = dir ? gi_b  : gi_f;
    ull* hcom = dir ? hcom_b : hcom_f;

    // ---- stage weights into the register file: 6 rows x 8 float4 = 192 floats/lane ----
    float4 wreg[6][8];
    #pragma unroll
    for (int j = 0; j < 6; ++j) {
        const int wgrow = g + 32 * j;
        const int grow  = ((wgrow >> 6) << 8) + (w << 6) + (wgrow & 63);
        const float4* src = (const float4*)(Whh + (size_t)grow * NH + (q << 5));
        #pragma unroll
        for (int c = 0; c < 8; ++c) wreg[j][c] = src[c];
    }

    __shared__ float4 h4[64];          // h state (256 f32)
    __shared__ float  ghs[192];
    __shared__ float  bh_s[192];
    float* h_s = (float*)h4;

    if (tid < 192) {
        const int grow = ((tid >> 6) << 8) + (w << 6) + (tid & 63);
        bh_s[tid] = bhh[grow];
    }
    h_s[tid] = 0.f;
    __syncthreads();

    for (int t = 0; t < NS; ++t) {
        const int s = dir ? (NS - 1 - t) : t;

        // input-gate prefetch (independent of h) by the gate wave
        float gir = 0.f, giz = 0.f, gin = 0.f;
        if (tid < 64) {
            const float* gp = gi + (size_t)s * G3 + (w << 6) + tid;
            gir = gp[0]; giz = gp[NH]; gin = gp[2 * NH];
        }

        // ---- matvec: read h cols [32q,32q+32) (q-rotated -> conflict-free) ----
        float4 hv[8];
        #pragma unroll
        for (int c = 0; c < 8; ++c) {
            const int kk = (c + q) & 7;
            hv[kk] = h4[(q << 3) + kk];
        }
        #pragma unroll
        for (int j = 0; j < 6; ++j) {
            float4 a = make_float4(0.f, 0.f, 0.f, 0.f);
            #pragma unroll
            for (int c = 0; c < 8; ++c) {
                a.x += wreg[j][c].x * hv[c].x;
                a.y += wreg[j][c].y * hv[c].y;
                a.z += wreg[j][c].z * hv[c].z;
                a.w += wreg[j][c].w * hv[c].w;
            }
            float r = (a.x + a.y) + (a.z + a.w);
            r = dpp_add<0x0B1>(r);   // quad_perm [1,0,3,2]  (sum lane^1)
            r = dpp_add<0x04E>(r);   // quad_perm [2,3,0,1]  (sum lane^2)
            r = dpp_add<0x141>(r);   // row_half_mirror      (sum other quad)
            if (q == 0) {
                const int wgrow = g + 32 * j;
                ghs[wgrow] = r + bh_s[wgrow];
            }
        }
        __syncthreads();   // S1: ghs ready; all matvec reads of h done

        if (tid < 64) {
            const int i = tid;
            const float r  = 1.f / (1.f + __expf(-(gir + ghs[i])));
            const float z  = 1.f / (1.f + __expf(-(giz + ghs[64 + i])));
            const float n  = tanhf(gin + r * ghs[128 + i]);
            const float hn = (1.f - z) * n + z * h_s[(w << 6) + i];
            out2[(size_t)s * (2 * NH) + dir * NH + (w << 6) + i] = hn;
            const ull pv = ((ull)(unsigned)(t + 1) << 32) | (ull)__float_as_uint(hn);
            // R1-proven publish primitive: relaxed agent-scope atomic store (non-RMW)
            __hip_atomic_store(&hcom[((t & 1) << 8) + (w << 6) + i], pv,
                               __ATOMIC_RELAXED, __HIP_MEMORY_SCOPE_AGENT);
            h_s[(w << 6) + i] = hn;
        } else if (t < NS - 1) {
            const int k   = tid - 64;                       // 0..191
            const int idx = (k < (w << 6)) ? k : k + 64;    // skip own 64
            const int slot = ((t & 1) << 8) + idx;
            const unsigned want = (unsigned)(t + 1);
            ull v;
            do {
                // R1-proven consume primitive: relaxed agent-scope atomic load (read-only)
                v = __hip_atomic_load(&hcom[slot], __ATOMIC_RELAXED, __HIP_MEMORY_SCOPE_AGENT);
            } while ((unsigned)(v >> 32) != want);
            h_s[idx] = __uint_as_float((unsigned)v);
        }
        __syncthreads();   // S2: h fully updated
    }
}

// ---------------- 4) scores[s] = dot(output[s], h_f + h_b) ----------------
__global__ __launch_bounds__(256) void scores_kernel(
    const float* __restrict__ outp, const float* __restrict__ out2,
    float* __restrict__ scores)
{
    const int s = blockIdx.x, m = threadIdx.x;
    float hs = out2[(size_t)(NS - 1) * (2 * NH) + m] + out2[NH + m];
    float v = outp[(size_t)s * NH + m] * hs;
    #pragma unroll
    for (int o = 32; o > 0; o >>= 1) v += __shfl_down(v, o);
    __shared__ float p[4];
    if ((m & 63) == 0) p[m >> 6] = v;
    __syncthreads();
    if (m == 0) scores[s] = p[0] + p[1] + p[2] + p[3];
}

// ---------------- 5) softmax over 2049 scores (in place) ----------------
__global__ __launch_bounds__(1024) void softmax_kernel(float* __restrict__ sc)
{
    const int tid = threadIdx.x;
    __shared__ float red[16];
    float x0 = (tid < NS) ? sc[tid] : -3.0e38f;
    float x1 = (tid + 1024 < NS) ? sc[tid + 1024] : -3.0e38f;
    float mx = fmaxf(x0, x1);
    #pragma unroll
    for (int o = 32; o > 0; o >>= 1) mx = fmaxf(mx, __shfl_xor(mx, o));
    if ((tid & 63) == 0) red[tid >> 6] = mx;
    __syncthreads();
    if (tid == 0) {
        float m = red[0];
        for (int i = 1; i < 16; ++i) m = fmaxf(m, red[i]);
        red[0] = m;
    }
    __syncthreads();
    const float gmax = red[0];
    float e0 = (tid < NS) ? __expf(x0 - gmax) : 0.f;
    float e1 = (tid + 1024 < NS) ? __expf(x1 - gmax) : 0.f;
    float sm = e0 + e1;
    #pragma unroll
    for (int o = 32; o > 0; o >>= 1) sm += __shfl_xor(sm, o);
    __syncthreads();
    if ((tid & 63) == 0) red[tid >> 6] = sm;
    __syncthreads();
    if (tid == 0) {
        float su = 0.f;
        for (int i = 0; i < 16; ++i) su += red[i];
        red[1] = 1.f / su;
    }
    __syncthreads();
    const float inv = red[1];
    if (tid < NS) sc[tid] = e0 * inv;
    if (tid + 1024 < NS) sc[tid + 1024] = e1 * inv;
}

// ---------------- 6) ctx[m] += sum_s w[s]*output[s][m] ----------------
__global__ __launch_bounds__(256) void ctx_kernel(
    const float* __restrict__ outp, const float* __restrict__ w,
    float* __restrict__ ctx)
{
    const int m = threadIdx.x;
    const int s0 = blockIdx.x * 128;
    const int s1 = min(s0 + 128, NS);
    float acc = 0.f;
    for (int s = s0; s < s1; ++s) acc += w[s] * outp[(size_t)s * NH + m];
    atomicAdd(&ctx[m], acc);
}

// ---------------- 7) result + loss ----------------
__global__ __launch_bounds__(256) void final_kernel(
    const float* __restrict__ ctx, const float* __restrict__ Wo,
    const float* __restrict__ bo, const float* __restrict__ label,
    float* __restrict__ dout)
{
    const int m = threadIdx.x;
    float v = ctx[m] * Wo[m];
    #pragma unroll
    for (int o = 32; o > 0; o >>= 1) v += __shfl_down(v, o);
    __shared__ float p[4];
    if ((m & 63) == 0) p[m >> 6] = v;
    __syncthreads();
    if (m == 0) {
        float x = p[0] + p[1] + p[2] + p[3] + bo[0];
        float result = 1.f / (1.f + __expf(-x));
        float d = label[0] - result;
        dout[(size_t)NS * NH]     = d * d;
        dout[(size_t)NS * NH + 1] = result;
    }
}

extern "C" void kernel_launch(void* const* d_in, const int* in_sizes, int n_in,
                              void* d_out, int out_size, void* d_ws, size_t ws_size,
                              hipStream_t stream)
{
    const int*   otok  = (const int*)d_in[0];
    const int*   rtok  = (const int*)d_in[1];
    const int*   rlen  = (const int*)d_in[2];
    const float* label = (const float*)d_in[3];
    const float* embed = (const float*)d_in[4];
    const float* Wih_f = (const float*)d_in[5];
    const float* Whh_f = (const float*)d_in[6];
    const float* bih_f = (const float*)d_in[7];
    const float* bhh_f = (const float*)d_in[8];
    const float* Wih_b = (const float*)d_in[9];
    const float* Whh_b = (const float*)d_in[10];
    const float* bih_b = (const float*)d_in[11];
    const float* bhh_b = (const float*)d_in[12];
    const float* Wl    = (const float*)d_in[13];
    const float* bl    = (const float*)d_in[14];
    const float* Wo    = (const float*)d_in[15];
    const float* bo    = (const float*)d_in[16];

    char* ws = (char*)d_ws;
    ull* hcom_f = (ull*)(ws + OFF_HCOM_F);
    ull* hcom_b = (ull*)(ws + OFF_HCOM_B);
    float* ctx    = (float*)(ws + OFF_CTX);
    unsigned int* claim = (unsigned int*)(ws + OFF_CLAIM);
    float* scores = (float*)(ws + OFF_SCORES);
    float* X      = (float*)(ws + OFF_X);
    float* gi_f   = (float*)(ws + OFF_GI_F);
    float* gi_b   = (float*)(ws + OFF_GI_B);
    float* out2   = (float*)(ws + OFF_OUT2);
    float* outp   = (float*)d_out;

    // zero comm tags + ctx + claim counters (graph-capture-safe)
    (void)hipMemsetAsync(d_ws, 0, ZERO_BYTES, stream);

    embed_sum_kernel<<<NS, 320, 0, stream>>>(otok, rtok, rlen, embed, X);

    gemm_abt<<<dim3(33, 12), 256, 0, stream>>>(X, Wih_f, bih_f, gi_f, NS, G3, NE, G3);
    gemm_abt<<<dim3(33, 12), 256, 0, stream>>>(X, Wih_b, bih_b, gi_b, NS, G3, NE, G3);

    gru_kernel<<<512, 256, 0, stream>>>(Whh_f, bhh_f, Whh_b, bhh_b,
                                        gi_f, gi_b, out2, hcom_f, hcom_b, claim);

    gemm_abt<<<dim3(33, 4), 256, 0, stream>>>(out2, Wl, bl, outp, NS, NH, 2 * NH, NH);

    scores_kernel<<<NS, 256, 0, stream>>>(outp, out2, scores);
    softmax_kernel<<<1, 1024, 0, stream>>>(scores);
    ctx_kernel<<<(NS + 127) / 128, 256, 0, stream>>>(outp, scores, ctx);
    final_kernel<<<1, 256, 0, stream>>>(ctx, Wo, bo, label, (float*)d_out);
}

// Round 6
// 4294.230 us; speedup vs baseline: 3.3243x; 3.2949x over previous
//
#include <hip/hip_runtime.h>
#include <cstdint>
#include <cstddef>

#define NV 50000
#define NE 300
#define NH 256
#define NR 2048
#define NL0 128
#define NLR 64
#define NS 2049      // R + 1
#define G3 768       // 3*H

typedef unsigned long long ull;

// ---------------- workspace layout ----------------
static constexpr size_t alignUp(size_t x, size_t a) { return (x + a - 1) / a * a; }
static constexpr size_t OFF_HCOM_F = 0;                         // 2*256 u64 (double-buffered)
static constexpr size_t OFF_HCOM_B = 4096;                      // 2*256 u64
static constexpr size_t OFF_CTX    = 8192;                      // 256 f32
static constexpr size_t ZERO_BYTES = 9232;
static constexpr size_t OFF_SCORES = 9472;                      // 2049 f32
static constexpr size_t OFF_X      = alignUp(OFF_SCORES + (size_t)NS*4, 256);   // 2049*300 f32
static constexpr size_t OFF_GI_F   = alignUp(OFF_X + (size_t)NS*NE*4, 256);     // 2049*768 f32
static constexpr size_t OFF_GI_B   = alignUp(OFF_GI_F + (size_t)NS*G3*4, 256);  // 2049*768 f32
static constexpr size_t OFF_OUT2   = alignUp(OFF_GI_B + (size_t)NS*G3*4, 256);  // 2049*512 f32

// ---------------- 1) X = [orig_sum ; reply_sums] ----------------
__global__ __launch_bounds__(320) void embed_sum_kernel(
    const int* __restrict__ otok, const int* __restrict__ rtok,
    const int* __restrict__ rlen, const float* __restrict__ embed,
    float* __restrict__ X)
{
    const int b = blockIdx.x;      // 0..2048
    const int e = threadIdx.x;     // < 300 active
    if (e >= NE) return;
    float acc = 0.f;
    if (b == 0) {
        for (int t = 0; t < NL0; ++t) {
            int tok = otok[t];
            acc += embed[(size_t)tok * NE + e];
        }
    } else {
        const int r = b - 1;
        const int L = rlen[r];
        const int* tr = rtok + (size_t)r * NLR;
        for (int t = 0; t < L; ++t) {
            int tok = tr[t];
            acc += embed[(size_t)tok * NE + e];
        }
    }
    X[(size_t)b * NE + e] = acc;
}

// ---------------- 2) C[M,N] = A[M,K] @ B[N,K]^T + bias[N] ----------------
__global__ __launch_bounds__(256) void gemm_abt(
    const float* __restrict__ A, const float* __restrict__ B,
    const float* __restrict__ bias, float* __restrict__ C,
    int M, int N, int K, int ldc)
{
    __shared__ float As[16][65];
    __shared__ float Bs[16][65];
    const int bm = blockIdx.x * 64, bn = blockIdx.y * 64;
    const int tid = threadIdx.x;
    const int tx = tid & 15, ty = tid >> 4;
    float acc[4][4] = {};
    for (int k0 = 0; k0 < K; k0 += 16) {
        #pragma unroll
        for (int i = 0; i < 4; ++i) {
            int l = tid + 256 * i;
            int mm = l >> 4, kk = l & 15;
            int gm = bm + mm, gk = k0 + kk;
            As[kk][mm] = (gm < M && gk < K) ? A[(size_t)gm * K + gk] : 0.f;
            int gn = bn + mm;
            Bs[kk][mm] = (gk < K) ? B[(size_t)gn * K + gk] : 0.f;
        }
        __syncthreads();
        #pragma unroll
        for (int kk = 0; kk < 16; ++kk) {
            float a0 = As[kk][ty], a1 = As[kk][ty+16], a2 = As[kk][ty+32], a3 = As[kk][ty+48];
            float b0 = Bs[kk][tx], b1 = Bs[kk][tx+16], b2 = Bs[kk][tx+32], b3 = Bs[kk][tx+48];
            acc[0][0] += a0*b0; acc[0][1] += a0*b1; acc[0][2] += a0*b2; acc[0][3] += a0*b3;
            acc[1][0] += a1*b0; acc[1][1] += a1*b1; acc[1][2] += a1*b2; acc[1][3] += a1*b3;
            acc[2][0] += a2*b0; acc[2][1] += a2*b1; acc[2][2] += a2*b2; acc[2][3] += a2*b3;
            acc[3][0] += a3*b0; acc[3][1] += a3*b1; acc[3][2] += a3*b2; acc[3][3] += a3*b3;
        }
        __syncthreads();
    }
    #pragma unroll
    for (int i = 0; i < 4; ++i) {
        int gm = bm + ty + 16 * i;
        if (gm >= M) continue;
        #pragma unroll
        for (int j = 0; j < 4; ++j) {
            int gn = bn + tx + 16 * j;
            C[(size_t)gm * ldc + gn] = acc[i][j] + bias[gn];
        }
    }
}

// ---------------- 3) bidirectional GRU recurrence ----------------
// R1-proven skeleton: 32 blocks x 256 threads, NO XCD pinning (scattered dispatch was
// the fast config). dir = blk>>4, w = blk&15. Each WG: 16 outputs, 48 Whh rows in LDS
// fp32 (~50 KB). Exchange: tagged u64, parity double-buffered, RELAXED+AGENT atomic
// store/load (R1-proven live+correct primitives).
// NEW vs R1: consolidated polling — ONLY wave 3 polls; each lane covers 4 slots with
// 4 batched in-flight loads per iteration (one RT for 4 slots). Poll streams 7680->1920.
__global__ __launch_bounds__(256, 1) void gru_kernel(
    const float* __restrict__ Whh_f, const float* __restrict__ bhh_f,
    const float* __restrict__ Whh_b, const float* __restrict__ bhh_b,
    const float* __restrict__ gi_f, const float* __restrict__ gi_b,
    float* __restrict__ out2,
    ull* __restrict__ hcom_f, ull* __restrict__ hcom_b)
{
    const int dir = blockIdx.x >> 4;
    const int w   = blockIdx.x & 15;
    const int tid = threadIdx.x;

    const float* Whh = dir ? Whh_b : Whh_f;
    const float* bhh = dir ? bhh_b : bhh_f;
    const float* gi  = dir ? gi_b  : gi_f;
    ull* hcom = dir ? hcom_b : hcom_f;

    // wP[row][q*16+c], row stride 65 float4: b128 reads land at the 8-cyc structural min
    __shared__ float4 wP[48 * 65];     // 49,920 B
    __shared__ float4 h4[64];          // h state (256 f32)
    __shared__ float  ghs[48];
    __shared__ float  bh_s[48];
    float* h_s = (float*)h4;

    // stage weights: 48 rows x 64 float4; grow = (lr/16)*256 + 16w + (lr%16)
    for (int idx = tid; idx < 48 * 64; idx += 256) {
        const int k4 = idx & 63, lr = idx >> 6;
        const int grow = ((lr >> 4) << 8) + (w << 4) + (lr & 15);
        wP[lr * 65 + k4] = *(const float4*)(Whh + (size_t)grow * NH + (k4 << 2));
    }
    if (tid < 48) {
        const int grow = ((tid >> 4) << 8) + (w << 4) + (tid & 15);
        bh_s[tid] = bhh[grow];
    }
    h_s[tid] = 0.f;
    __syncthreads();

    for (int t = 0; t < NS; ++t) {
        const int s = dir ? (NS - 1 - t) : t;

        // gate lanes (192..207): prefetch gi (independent of h; hidden under matvec)
        float gir = 0.f, giz = 0.f, gin = 0.f;
        if (tid >= 192 && tid < 208) {
            const int i = tid - 192;
            const float* gp = gi + (size_t)s * G3 + (w << 4) + i;
            gir = gp[0]; giz = gp[NH]; gin = gp[2 * NH];
        }

        // waves 0-2: matvec. row = tid>>2 (48 rows, 4 lanes each), q = tid&3,
        // cols [64q, 64q+64) = 16 float4. h4 reads are 16-lane broadcasts (free).
        if (tid < 192) {
            const int row = tid >> 2, q = tid & 3;
            const float4* wrow = &wP[row * 65 + (q << 4)];
            const float4* hrow = &h4[q << 4];
            float4 a = make_float4(0.f, 0.f, 0.f, 0.f);
            #pragma unroll
            for (int c = 0; c < 16; ++c) {
                const float4 wv = wrow[c], hv = hrow[c];
                a.x += wv.x * hv.x; a.y += wv.y * hv.y;
                a.z += wv.z * hv.z; a.w += wv.w * hv.w;
            }
            float r = (a.x + a.y) + (a.z + a.w);
            r += __shfl_xor(r, 1);
            r += __shfl_xor(r, 2);
            if (q == 0) ghs[row] = r + bh_s[row];
        }
        __syncthreads();   // S1: ghs ready; all matvec reads of h done

        // gate lanes: gates + publish own 16 elements
        if (tid >= 192 && tid < 208) {
            const int i = tid - 192;
            const float r  = 1.f / (1.f + __expf(-(gir + ghs[i])));
            const float z  = 1.f / (1.f + __expf(-(giz + ghs[16 + i])));
            const float n  = tanhf(gin + r * ghs[32 + i]);
            const float hn = (1.f - z) * n + z * h_s[(w << 4) + i];
            out2[(size_t)s * (2 * NH) + dir * NH + (w << 4) + i] = hn;
            const ull pv = ((ull)(unsigned)(t + 1) << 32) | (ull)__float_as_uint(hn);
            __hip_atomic_store(&hcom[((t & 1) << 8) + (w << 4) + i], pv,
                               __ATOMIC_RELAXED, __HIP_MEMORY_SCOPE_AGENT);
            h_s[(w << 4) + i] = hn;
        }

        // consolidated poll: wave 3 only. lane lam<60 covers remote slots 4lam..4lam+3
        // (240 = 60*4 remote slots; own 16 skipped). 4 loads batched in flight per iter.
        if (t < NS - 1 && tid >= 192) {
            const int lam = tid - 192;
            if (lam < 60) {
                const int r0 = lam << 2;
                const int own = w << 4;
                int k[4];
                #pragma unroll
                for (int j = 0; j < 4; ++j) {
                    const int r = r0 + j;
                    k[j] = (r < own) ? r : r + 16;
                }
                const int base = (t & 1) << 8;
                const unsigned want = (unsigned)(t + 1);
                ull v0, v1, v2, v3;
                do {
                    v0 = __hip_atomic_load(&hcom[base + k[0]], __ATOMIC_RELAXED, __HIP_MEMORY_SCOPE_AGENT);
                    v1 = __hip_atomic_load(&hcom[base + k[1]], __ATOMIC_RELAXED, __HIP_MEMORY_SCOPE_AGENT);
                    v2 = __hip_atomic_load(&hcom[base + k[2]], __ATOMIC_RELAXED, __HIP_MEMORY_SCOPE_AGENT);
                    v3 = __hip_atomic_load(&hcom[base + k[3]], __ATOMIC_RELAXED, __HIP_MEMORY_SCOPE_AGENT);
                } while (((unsigned)(v0 >> 32) != want) | ((unsigned)(v1 >> 32) != want) |
                         ((unsigned)(v2 >> 32) != want) | ((unsigned)(v3 >> 32) != want));
                h_s[k[0]] = __uint_as_float((unsigned)v0);
                h_s[k[1]] = __uint_as_float((unsigned)v1);
                h_s[k[2]] = __uint_as_float((unsigned)v2);
                h_s[k[3]] = __uint_as_float((unsigned)v3);
            }
        }
        __syncthreads();   // S2: h fully updated
    }
}

// ---------------- 4) scores[s] = dot(output[s], h_f + h_b) ----------------
__global__ __launch_bounds__(256) void scores_kernel(
    const float* __restrict__ outp, const float* __restrict__ out2,
    float* __restrict__ scores)
{
    const int s = blockIdx.x, m = threadIdx.x;
    float hs = out2[(size_t)(NS - 1) * (2 * NH) + m] + out2[NH + m];
    float v = outp[(size_t)s * NH + m] * hs;
    #pragma unroll
    for (int o = 32; o > 0; o >>= 1) v += __shfl_down(v, o);
    __shared__ float p[4];
    if ((m & 63) == 0) p[m >> 6] = v;
    __syncthreads();
    if (m == 0) scores[s] = p[0] + p[1] + p[2] + p[3];
}

// ---------------- 5) softmax over 2049 scores (in place) ----------------
__global__ __launch_bounds__(1024) void softmax_kernel(float* __restrict__ sc)
{
    const int tid = threadIdx.x;
    __shared__ float red[16];
    float x0 = (tid < NS) ? sc[tid] : -3.0e38f;
    float x1 = (tid + 1024 < NS) ? sc[tid + 1024] : -3.0e38f;
    float mx = fmaxf(x0, x1);
    #pragma unroll
    for (int o = 32; o > 0; o >>= 1) mx = fmaxf(mx, __shfl_xor(mx, o));
    if ((tid & 63) == 0) red[tid >> 6] = mx;
    __syncthreads();
    if (tid == 0) {
        float m = red[0];
        for (int i = 1; i < 16; ++i) m = fmaxf(m, red[i]);
        red[0] = m;
    }
    __syncthreads();
    const float gmax = red[0];
    float e0 = (tid < NS) ? __expf(x0 - gmax) : 0.f;
    float e1 = (tid + 1024 < NS) ? __expf(x1 - gmax) : 0.f;
    float sm = e0 + e1;
    #pragma unroll
    for (int o = 32; o > 0; o >>= 1) sm += __shfl_xor(sm, o);
    __syncthreads();
    if ((tid & 63) == 0) red[tid >> 6] = sm;
    __syncthreads();
    if (tid == 0) {
        float su = 0.f;
        for (int i = 0; i < 16; ++i) su += red[i];
        red[1] = 1.f / su;
    }
    __syncthreads();
    const float inv = red[1];
    if (tid < NS) sc[tid] = e0 * inv;
    if (tid + 1024 < NS) sc[tid + 1024] = e1 * inv;
}

// ---------------- 6) ctx[m] += sum_s w[s]*output[s][m] ----------------
__global__ __launch_bounds__(256) void ctx_kernel(
    const float* __restrict__ outp, const float* __restrict__ w,
    float* __restrict__ ctx)
{
    const int m = threadIdx.x;
    const int s0 = blockIdx.x * 128;
    const int s1 = min(s0 + 128, NS);
    float acc = 0.f;
    for (int s = s0; s < s1; ++s) acc += w[s] * outp[(size_t)s * NH + m];
    atomicAdd(&ctx[m], acc);
}

// ---------------- 7) result + loss ----------------
__global__ __launch_bounds__(256) void final_kernel(
    const float* __restrict__ ctx, const float* __restrict__ Wo,
    const float* __restrict__ bo, const float* __restrict__ label,
    float* __restrict__ dout)
{
    const int m = threadIdx.x;
    float v = ctx[m] * Wo[m];
    #pragma unroll
    for (int o = 32; o > 0; o >>= 1) v += __shfl_down(v, o);
    __shared__ float p[4];
    if ((m & 63) == 0) p[m >> 6] = v;
    __syncthreads();
    if (m == 0) {
        float x = p[0] + p[1] + p[2] + p[3] + bo[0];
        float result = 1.f / (1.f + __expf(-x));
        float d = label[0] - result;
        dout[(size_t)NS * NH]     = d * d;
        dout[(size_t)NS * NH + 1] = result;
    }
}

extern "C" void kernel_launch(void* const* d_in, const int* in_sizes, int n_in,
                              void* d_out, int out_size, void* d_ws, size_t ws_size,
                              hipStream_t stream)
{
    const int*   otok  = (const int*)d_in[0];
    const int*   rtok  = (const int*)d_in[1];
    const int*   rlen  = (const int*)d_in[2];
    const float* label = (const float*)d_in[3];
    const float* embed = (const float*)d_in[4];
    const float* Wih_f = (const float*)d_in[5];
    const float* Whh_f = (const float*)d_in[6];
    const float* bih_f = (const float*)d_in[7];
    const float* bhh_f = (const float*)d_in[8];
    const float* Wih_b = (const float*)d_in[9];
    const float* Whh_b = (const float*)d_in[10];
    const float* bih_b = (const float*)d_in[11];
    const float* bhh_b = (const float*)d_in[12];
    const float* Wl    = (const float*)d_in[13];
    const float* bl    = (const float*)d_in[14];
    const float* Wo    = (const float*)d_in[15];
    const float* bo    = (const float*)d_in[16];

    char* ws = (char*)d_ws;
    ull* hcom_f = (ull*)(ws + OFF_HCOM_F);
    ull* hcom_b = (ull*)(ws + OFF_HCOM_B);
    float* ctx    = (float*)(ws + OFF_CTX);
    float* scores = (float*)(ws + OFF_SCORES);
    float* X      = (float*)(ws + OFF_X);
    float* gi_f   = (float*)(ws + OFF_GI_F);
    float* gi_b   = (float*)(ws + OFF_GI_B);
    float* out2   = (float*)(ws + OFF_OUT2);
    float* outp   = (float*)d_out;

    // zero comm tags + ctx (graph-capture-safe)
    (void)hipMemsetAsync(d_ws, 0, ZERO_BYTES, stream);

    embed_sum_kernel<<<NS, 320, 0, stream>>>(otok, rtok, rlen, embed, X);

    gemm_abt<<<dim3(33, 12), 256, 0, stream>>>(X, Wih_f, bih_f, gi_f, NS, G3, NE, G3);
    gemm_abt<<<dim3(33, 12), 256, 0, stream>>>(X, Wih_b, bih_b, gi_b, NS, G3, NE, G3);

    gru_kernel<<<32, 256, 0, stream>>>(Whh_f, bhh_f, Whh_b, bhh_b,
                                       gi_f, gi_b, out2, hcom_f, hcom_b);

    gemm_abt<<<dim3(33, 4), 256, 0, stream>>>(out2, Wl, bl, outp, NS, NH, 2 * NH, NH);

    scores_kernel<<<NS, 256, 0, stream>>>(outp, out2, scores);
    softmax_kernel<<<1, 1024, 0, stream>>>(scores);
    ctx_kernel<<<(NS + 127) / 128, 256, 0, stream>>>(outp, scores, ctx);
    final_kernel<<<1, 256, 0, stream>>>(ctx, Wo, bo, label, (float*)d_out);
}

// Round 8
// 3852.156 us; speedup vs baseline: 3.7058x; 1.1148x over previous
//
#include <hip/hip_runtime.h>
#include <cstdint>
#include <cstddef>

#define NV 50000
#define NE 300
#define NH 256
#define NR 2048
#define NL0 128
#define NLR 64
#define NS 2049      // R + 1
#define G3 768       // 3*H

typedef unsigned long long ull;

// ---------------- workspace layout ----------------
static constexpr size_t alignUp(size_t x, size_t a) { return (x + a - 1) / a * a; }
static constexpr size_t OFF_HCOM_F = 0;                         // 2*256 u64 (double-buffered)
static constexpr size_t OFF_HCOM_B = 4096;                      // 2*256 u64
static constexpr size_t OFF_CTX    = 8192;                      // 256 f32
static constexpr size_t ZERO_BYTES = 9232;
static constexpr size_t OFF_SCORES = 9472;                      // 2049 f32
static constexpr size_t OFF_X      = alignUp(OFF_SCORES + (size_t)NS*4, 256);   // 2049*300 f32
static constexpr size_t OFF_GI_F   = alignUp(OFF_X + (size_t)NS*NE*4, 256);     // 2049*768 f32
static constexpr size_t OFF_GI_B   = alignUp(OFF_GI_F + (size_t)NS*G3*4, 256);  // 2049*768 f32
static constexpr size_t OFF_OUT2   = alignUp(OFF_GI_B + (size_t)NS*G3*4, 256);  // 2049*512 f32

// ---------------- 1) X = [orig_sum ; reply_sums] ----------------
__global__ __launch_bounds__(320) void embed_sum_kernel(
    const int* __restrict__ otok, const int* __restrict__ rtok,
    const int* __restrict__ rlen, const float* __restrict__ embed,
    float* __restrict__ X)
{
    const int b = blockIdx.x;      // 0..2048
    const int e = threadIdx.x;     // < 300 active
    if (e >= NE) return;
    float acc = 0.f;
    if (b == 0) {
        for (int t = 0; t < NL0; ++t) {
            int tok = otok[t];
            acc += embed[(size_t)tok * NE + e];
        }
    } else {
        const int r = b - 1;
        const int L = rlen[r];
        const int* tr = rtok + (size_t)r * NLR;
        for (int t = 0; t < L; ++t) {
            int tok = tr[t];
            acc += embed[(size_t)tok * NE + e];
        }
    }
    X[(size_t)b * NE + e] = acc;
}

// ---------------- 2) C[M,N] = A[M,K] @ B[N,K]^T + bias[N] ----------------
__global__ __launch_bounds__(256) void gemm_abt(
    const float* __restrict__ A, const float* __restrict__ B,
    const float* __restrict__ bias, float* __restrict__ C,
    int M, int N, int K, int ldc)
{
    __shared__ float As[16][65];
    __shared__ float Bs[16][65];
    const int bm = blockIdx.x * 64, bn = blockIdx.y * 64;
    const int tid = threadIdx.x;
    const int tx = tid & 15, ty = tid >> 4;
    float acc[4][4] = {};
    for (int k0 = 0; k0 < K; k0 += 16) {
        #pragma unroll
        for (int i = 0; i < 4; ++i) {
            int l = tid + 256 * i;
            int mm = l >> 4, kk = l & 15;
            int gm = bm + mm, gk = k0 + kk;
            As[kk][mm] = (gm < M && gk < K) ? A[(size_t)gm * K + gk] : 0.f;
            int gn = bn + mm;
            Bs[kk][mm] = (gk < K) ? B[(size_t)gn * K + gk] : 0.f;
        }
        __syncthreads();
        #pragma unroll
        for (int kk = 0; kk < 16; ++kk) {
            float a0 = As[kk][ty], a1 = As[kk][ty+16], a2 = As[kk][ty+32], a3 = As[kk][ty+48];
            float b0 = Bs[kk][tx], b1 = Bs[kk][tx+16], b2 = Bs[kk][tx+32], b3 = Bs[kk][tx+48];
            acc[0][0] += a0*b0; acc[0][1] += a0*b1; acc[0][2] += a0*b2; acc[0][3] += a0*b3;
            acc[1][0] += a1*b0; acc[1][1] += a1*b1; acc[1][2] += a1*b2; acc[1][3] += a1*b3;
            acc[2][0] += a2*b0; acc[2][1] += a2*b1; acc[2][2] += a2*b2; acc[2][3] += a2*b3;
            acc[3][0] += a3*b0; acc[3][1] += a3*b1; acc[3][2] += a3*b2; acc[3][3] += a3*b3;
        }
        __syncthreads();
    }
    #pragma unroll
    for (int i = 0; i < 4; ++i) {
        int gm = bm + ty + 16 * i;
        if (gm >= M) continue;
        #pragma unroll
        for (int j = 0; j < 4; ++j) {
            int gn = bn + tx + 16 * j;
            C[(size_t)gm * ldc + gn] = acc[i][j] + bias[gn];
        }
    }
}

// ---------------- 3) bidirectional GRU recurrence ----------------
// EXACT R6 structure (measured-good) with ONE change: conflict-free LDS weight layout.
// 32 blocks x 256 threads, scattered dispatch. dir=blk>>4, w=blk&15.
// Matvec lane tid<192: row=tid>>2 (48 rows), q=tid&3, cols [64q,64q+64).
// NEW layout wT[c*192 + tid]: at inner step c each wave reads 64 CONSECUTIVE float4s
// (1024 B linear) -> ds_read_b128 at the 8-cyc structural floor, ~zero bank conflicts
// (R6's wP[row*65+q*16+c] caused 7.7e7 conflict-cycles = ~0.49 us/step).
// Exchange: tagged u64, parity double-buffered, RELAXED+AGENT store/load (R1-proven);
// wave-3 consolidated poll, 4 batched slots/lane (R6-proven).
__global__ __launch_bounds__(256, 1) void gru_kernel(
    const float* __restrict__ Whh_f, const float* __restrict__ bhh_f,
    const float* __restrict__ Whh_b, const float* __restrict__ bhh_b,
    const float* __restrict__ gi_f, const float* __restrict__ gi_b,
    float* __restrict__ out2,
    ull* __restrict__ hcom_f, ull* __restrict__ hcom_b)
{
    const int dir = blockIdx.x >> 4;
    const int w   = blockIdx.x & 15;
    const int tid = threadIdx.x;

    const float* Whh = dir ? Whh_b : Whh_f;
    const float* bhh = dir ? bhh_b : bhh_f;
    const float* gi  = dir ? gi_b  : gi_f;
    ull* hcom = dir ? hcom_b : hcom_f;

    __shared__ float4 wT[16 * 192];    // [c][lane] 49,152 B — conflict-free layout
    __shared__ float4 h4[64];          // h state (256 f32)
    __shared__ float  ghs[48];
    __shared__ float  bh_s[48];
    float* h_s = (float*)h4;

    // stage weights: slot (c, l) holds Whh[grow(l>>2)][(l&3)*16 + c] as float4
    for (int idx = tid; idx < 16 * 192; idx += 256) {
        const int c = idx / 192;
        const int l = idx - c * 192;           // 0..191
        const int row = l >> 2, q = l & 3;
        const int grow = ((row >> 4) << 8) + (w << 4) + (row & 15);
        wT[idx] = *(const float4*)(Whh + (size_t)grow * NH + (((q << 4) + c) << 2));
    }
    if (tid < 48) {
        const int grow = ((tid >> 4) << 8) + (w << 4) + (tid & 15);
        bh_s[tid] = bhh[grow];
    }
    h_s[tid] = 0.f;
    __syncthreads();

    for (int t = 0; t < NS; ++t) {
        const int s = dir ? (NS - 1 - t) : t;

        // gate lanes (192..207): prefetch gi (independent of h; hidden under matvec)
        float gir = 0.f, giz = 0.f, gin = 0.f;
        if (tid >= 192 && tid < 208) {
            const int i = tid - 192;
            const float* gp = gi + (size_t)s * G3 + (w << 4) + i;
            gir = gp[0]; giz = gp[NH]; gin = gp[2 * NH];
        }

        // waves 0-2: matvec. Lane reads wT[c*192+tid] (consecutive b128, conflict-free)
        // and h4[(q<<4)+c] (4-address broadcast, free).
        if (tid < 192) {
            const int q = tid & 3;
            float4 a = make_float4(0.f, 0.f, 0.f, 0.f);
            #pragma unroll
            for (int c = 0; c < 16; ++c) {
                const float4 wv = wT[c * 192 + tid];
                const float4 hv = h4[(q << 4) + c];
                a.x += wv.x * hv.x; a.y += wv.y * hv.y;
                a.z += wv.z * hv.z; a.w += wv.w * hv.w;
            }
            float r = (a.x + a.y) + (a.z + a.w);
            r += __shfl_xor(r, 1);
            r += __shfl_xor(r, 2);
            if (q == 0) {
                const int row = tid >> 2;
                ghs[row] = r + bh_s[row];
            }
        }
        __syncthreads();   // S1: ghs ready; all matvec reads of h done

        // gate lanes: gates + publish own 16 elements
        if (tid >= 192 && tid < 208) {
            const int i = tid - 192;
            const float r  = 1.f / (1.f + __expf(-(gir + ghs[i])));
            const float z  = 1.f / (1.f + __expf(-(giz + ghs[16 + i])));
            const float n  = tanhf(gin + r * ghs[32 + i]);
            const float hn = (1.f - z) * n + z * h_s[(w << 4) + i];
            out2[(size_t)s * (2 * NH) + dir * NH + (w << 4) + i] = hn;
            const ull pv = ((ull)(unsigned)(t + 1) << 32) | (ull)__float_as_uint(hn);
            __hip_atomic_store(&hcom[((t & 1) << 8) + (w << 4) + i], pv,
                               __ATOMIC_RELAXED, __HIP_MEMORY_SCOPE_AGENT);
            h_s[(w << 4) + i] = hn;
        }

        // consolidated poll: wave 3 only. lane lam<60 covers remote slots 4lam..4lam+3
        if (t < NS - 1 && tid >= 192) {
            const int lam = tid - 192;
            if (lam < 60) {
                const int r0 = lam << 2;
                const int own = w << 4;
                int k[4];
                #pragma unroll
                for (int j = 0; j < 4; ++j) {
                    const int r = r0 + j;
                    k[j] = (r < own) ? r : r + 16;
                }
                const int base = (t & 1) << 8;
                const unsigned want = (unsigned)(t + 1);
                ull v0, v1, v2, v3;
                do {
                    v0 = __hip_atomic_load(&hcom[base + k[0]], __ATOMIC_RELAXED, __HIP_MEMORY_SCOPE_AGENT);
                    v1 = __hip_atomic_load(&hcom[base + k[1]], __ATOMIC_RELAXED, __HIP_MEMORY_SCOPE_AGENT);
                    v2 = __hip_atomic_load(&hcom[base + k[2]], __ATOMIC_RELAXED, __HIP_MEMORY_SCOPE_AGENT);
                    v3 = __hip_atomic_load(&hcom[base + k[3]], __ATOMIC_RELAXED, __HIP_MEMORY_SCOPE_AGENT);
                } while (((unsigned)(v0 >> 32) != want) | ((unsigned)(v1 >> 32) != want) |
                         ((unsigned)(v2 >> 32) != want) | ((unsigned)(v3 >> 32) != want));
                h_s[k[0]] = __uint_as_float((unsigned)v0);
                h_s[k[1]] = __uint_as_float((unsigned)v1);
                h_s[k[2]] = __uint_as_float((unsigned)v2);
                h_s[k[3]] = __uint_as_float((unsigned)v3);
            }
        }
        __syncthreads();   // S2: h fully updated
    }
}

// ---------------- 4) scores[s] = dot(output[s], h_f + h_b) ----------------
__global__ __launch_bounds__(256) void scores_kernel(
    const float* __restrict__ outp, const float* __restrict__ out2,
    float* __restrict__ scores)
{
    const int s = blockIdx.x, m = threadIdx.x;
    float hs = out2[(size_t)(NS - 1) * (2 * NH) + m] + out2[NH + m];
    float v = outp[(size_t)s * NH + m] * hs;
    #pragma unroll
    for (int o = 32; o > 0; o >>= 1) v += __shfl_down(v, o);
    __shared__ float p[4];
    if ((m & 63) == 0) p[m >> 6] = v;
    __syncthreads();
    if (m == 0) scores[s] = p[0] + p[1] + p[2] + p[3];
}

// ---------------- 5) softmax over 2049 scores (in place) ----------------
__global__ __launch_bounds__(1024) void softmax_kernel(float* __restrict__ sc)
{
    const int tid = threadIdx.x;
    __shared__ float red[16];
    float x0 = (tid < NS) ? sc[tid] : -3.0e38f;
    float x1 = (tid + 1024 < NS) ? sc[tid + 1024] : -3.0e38f;
    float mx = fmaxf(x0, x1);
    #pragma unroll
    for (int o = 32; o > 0; o >>= 1) mx = fmaxf(mx, __shfl_xor(mx, o));
    if ((tid & 63) == 0) red[tid >> 6] = mx;
    __syncthreads();
    if (tid == 0) {
        float m = red[0];
        for (int ii = 1; ii < 16; ++ii) m = fmaxf(m, red[ii]);
        red[0] = m;
    }
    __syncthreads();
    const float gmax = red[0];
    float e0 = (tid < NS) ? __expf(x0 - gmax) : 0.f;
    float e1 = (tid + 1024 < NS) ? __expf(x1 - gmax) : 0.f;
    float sm = e0 + e1;
    #pragma unroll
    for (int o = 32; o > 0; o >>= 1) sm += __shfl_xor(sm, o);
    __syncthreads();
    if ((tid & 63) == 0) red[tid >> 6] = sm;
    __syncthreads();
    if (tid == 0) {
        float su = 0.f;
        for (int ii = 0; ii < 16; ++ii) su += red[ii];
        red[1] = 1.f / su;
    }
    __syncthreads();
    const float inv = red[1];
    if (tid < NS) sc[tid] = e0 * inv;
    if (tid + 1024 < NS) sc[tid + 1024] = e1 * inv;
}

// ---------------- 6) ctx[m] += sum_s w[s]*output[s][m] ----------------
__global__ __launch_bounds__(256) void ctx_kernel(
    const float* __restrict__ outp, const float* __restrict__ w,
    float* __restrict__ ctx)
{
    const int m = threadIdx.x;
    const int s0 = blockIdx.x * 128;
    const int s1 = min(s0 + 128, NS);
    float acc = 0.f;
    for (int s = s0; s < s1; ++s) acc += w[s] * outp[(size_t)s * NH + m];
    atomicAdd(&ctx[m], acc);
}

// ---------------- 7) result + loss ----------------
__global__ __launch_bounds__(256) void final_kernel(
    const float* __restrict__ ctx, const float* __restrict__ Wo,
    const float* __restrict__ bo, const float* __restrict__ label,
    float* __restrict__ dout)
{
    const int m = threadIdx.x;
    float v = ctx[m] * Wo[m];
    #pragma unroll
    for (int o = 32; o > 0; o >>= 1) v += __shfl_down(v, o);
    __shared__ float p[4];
    if ((m & 63) == 0) p[m >> 6] = v;
    __syncthreads();
    if (m == 0) {
        float x = p[0] + p[1] + p[2] + p[3] + bo[0];
        float result = 1.f / (1.f + __expf(-x));
        float d = label[0] - result;
        dout[(size_t)NS * NH]     = d * d;
        dout[(size_t)NS * NH + 1] = result;
    }
}

extern "C" void kernel_launch(void* const* d_in, const int* in_sizes, int n_in,
                              void* d_out, int out_size, void* d_ws, size_t ws_size,
                              hipStream_t stream)
{
    const int*   otok  = (const int*)d_in[0];
    const int*   rtok  = (const int*)d_in[1];
    const int*   rlen  = (const int*)d_in[2];
    const float* label = (const float*)d_in[3];
    const float* embed = (const float*)d_in[4];
    const float* Wih_f = (const float*)d_in[5];
    const float* Whh_f = (const float*)d_in[6];
    const float* bih_f = (const float*)d_in[7];
    const float* bhh_f = (const float*)d_in[8];
    const float* Wih_b = (const float*)d_in[9];
    const float* Whh_b = (const float*)d_in[10];
    const float* bih_b = (const float*)d_in[11];
    const float* bhh_b = (const float*)d_in[12];
    const float* Wl    = (const float*)d_in[13];
    const float* bl    = (const float*)d_in[14];
    const float* Wo    = (const float*)d_in[15];
    const float* bo    = (const float*)d_in[16];

    char* ws = (char*)d_ws;
    ull* hcom_f = (ull*)(ws + OFF_HCOM_F);
    ull* hcom_b = (ull*)(ws + OFF_HCOM_B);
    float* ctx    = (float*)(ws + OFF_CTX);
    float* scores = (float*)(ws + OFF_SCORES);
    float* X      = (float*)(ws + OFF_X);
    float* gi_f   = (float*)(ws + OFF_GI_F);
    float* gi_b   = (float*)(ws + OFF_GI_B);
    float* out2   = (float*)(ws + OFF_OUT2);
    float* outp   = (float*)d_out;

    // zero comm tags + ctx (graph-capture-safe)
    (void)hipMemsetAsync(d_ws, 0, ZERO_BYTES, stream);

    embed_sum_kernel<<<NS, 320, 0, stream>>>(otok, rtok, rlen, embed, X);

    gemm_abt<<<dim3(33, 12), 256, 0, stream>>>(X, Wih_f, bih_f, gi_f, NS, G3, NE, G3);
    gemm_abt<<<dim3(33, 12), 256, 0, stream>>>(X, Wih_b, bih_b, gi_b, NS, G3, NE, G3);

    gru_kernel<<<32, 256, 0, stream>>>(Whh_f, bhh_f, Whh_b, bhh_b,
                                       gi_f, gi_b, out2, hcom_f, hcom_b);

    gemm_abt<<<dim3(33, 4), 256, 0, stream>>>(out2, Wl, bl, outp, NS, NH, 2 * NH, NH);

    scores_kernel<<<NS, 256, 0, stream>>>(outp, out2, scores);
    softmax_kernel<<<1, 1024, 0, stream>>>(scores);
    ctx_kernel<<<(NS + 127) / 128, 256, 0, stream>>>(outp, scores, ctx);
    final_kernel<<<1, 256, 0, stream>>>(ctx, Wo, bo, label, (float*)d_out);
}